// Round 10
// baseline (46.126 us; speedup 1.0000x reference)
//
#include <hip/hip_runtime.h>

// (B,N,F) = (8, 4096, 256), fp32 in/out. out = (B, 5, F).
constexpr int B = 8;
constexpr int N = 4096;
constexpr int F = 256;
constexpr int F4 = F / 4;        // 64 float4 per row
constexpr int CH = 64;           // chunks (blocks) per batch, both kernels
constexpr int R = N / CH;        // 64 rows per block
constexpr int W = R / 4;         // 16 rows per wave

typedef __attribute__((ext_vector_type(4))) float f32x4;

// Monotone float->uint mapping: f<g  <=>  sortable(f)<sortable(g)
__device__ __forceinline__ unsigned sortable_f32(float f) {
    unsigned u = __float_as_uint(f);
    return (u & 0x80000000u) ? ~u : (u | 0x80000000u);
}

__device__ __forceinline__ unsigned long long agent_load_u64(const unsigned long long* p) {
    return __hip_atomic_load(p, __ATOMIC_RELAXED, __HIP_MEMORY_SCOPE_AGENT);
}

// Pinned vector load: issued exactly here (volatile asm), result in fixed VGPRs,
// NOT tracked by the compiler's vmcnt bookkeeping (extra outstanding ops only make
// its waits stricter = safe). Caller must s_waitcnt vmcnt(0) before reading dst.
__device__ __forceinline__ void pinned_load4(f32x4& dst, const f32x4* p) {
    asm volatile("global_load_dwordx4 %0, %1, off" : "=v"(dst) : "v"(p));
}

// ---------------- KA: column partials of ref_flow + zero-init sync state ----------------
__global__ void __launch_bounds__(256, 4)
kA_colsum(const float* __restrict__ ref_flow, float* __restrict__ partial,
          int* __restrict__ cnt, unsigned long long* __restrict__ minbase,
          unsigned long long* __restrict__ maxbase) {
    const int b = blockIdx.x, chunk = blockIdx.y;
    const int t = threadIdx.x, wave = t >> 6, lane = t & 63;
    const int w16 = wave * W;
    __shared__ f32x4 red[4][F4];

    const f32x4* rbase = reinterpret_cast<const f32x4*>(ref_flow)
                       + ((size_t)b * N + (size_t)chunk * R) * F4;
    // Issue ALL 16 row loads back-to-back (asm-pinned: full stream in flight at once).
    f32x4 v[W];
    #pragma unroll
    for (int i = 0; i < W; ++i)
        pinned_load4(v[i], rbase + (size_t)(w16 + i) * F4 + lane);
    asm volatile("s_waitcnt vmcnt(0)" ::: "memory");
    __builtin_amdgcn_sched_barrier(0);

    f32x4 acc = {0.f, 0.f, 0.f, 0.f};
    #pragma unroll
    for (int i = 0; i < W; ++i) acc += v[i];
    red[wave][lane] = acc;
    __syncthreads();
    if (wave == 0) {
        f32x4 s = red[0][lane] + red[1][lane] + red[2][lane] + red[3][lane];
        reinterpret_cast<f32x4*>(partial)[((size_t)b * CH + chunk) * F4 + lane] = s;
    }
    // zero-init per-batch slots/counters (visible to KB via kernel-boundary flush)
    if (chunk == 0) {
        if (t < 3) minbase[(size_t)b * 16 + t] = 0ull;
        if (t < 2) maxbase[(size_t)b * 16 + t] = 0ull;
        if (t == 0) { cnt[b * 32] = 0; cnt[(B + b) * 32] = 0; }
    }
}

// ---------------- KB: sup prefetch (pinned) + S-reduce + dot1 + top3 -> spin barrier
//                      -> Tv + dot2 (registers) + top2 -> last-arriver gather ----------------
__global__ void __launch_bounds__(256, 4)
kB_rest(const float* __restrict__ ref_rgb, const float* __restrict__ ref_flow,
        const float* __restrict__ sup_rgb, const float* __restrict__ sup_flow,
        float* __restrict__ out, const float* __restrict__ partial,
        unsigned long long* __restrict__ minbase, unsigned long long* __restrict__ maxbase,
        int* __restrict__ cnt) {
    const int b = blockIdx.x, chunk = blockIdx.y;
    const int t = threadIdx.x, wave = t >> 6, lane = t & 63;
    const int w16 = wave * W;

    __shared__ float S[F];         // S vector, later reused as Tv
    __shared__ float scoreS[R];
    __shared__ int   chosen[3];
    __shared__ int   lastFlag;

    unsigned long long* minslot = minbase + (size_t)b * 16;
    unsigned long long* maxslot = maxbase + (size_t)b * 16;

    // 1) COLD sup_flow stream: 16 asm-pinned loads issued at kernel entry; they
    //    drain under S-reduce + dot1 + the spin. Registers guaranteed (VGPR cap 128).
    const f32x4* sbase = reinterpret_cast<const f32x4*>(sup_flow)
                       + ((size_t)b * N + (size_t)chunk * R) * F4;
    f32x4 sv[W];
    #pragma unroll
    for (int i = 0; i < W; ++i)
        pinned_load4(sv[i], sbase + (size_t)(w16 + i) * F4 + lane);

    // 2) Redundant S-reduce from partials (plain cached loads; boundary flushed them).
    {
        float sacc = 0.f;
        const float* pb = partial + (size_t)b * CH * F + t;
        #pragma unroll 8
        for (int p = 0; p < CH; ++p) sacc += pb[(size_t)p * F];
        S[t] = sacc;
    }
    __syncthreads();

    // 3) dot1: re-read my ref rows (L3-hit after KA), dot against S.
    const f32x4* rbase = reinterpret_cast<const f32x4*>(ref_flow)
                       + ((size_t)b * N + (size_t)chunk * R) * F4;
    {
        f32x4 s4 = reinterpret_cast<const f32x4*>(S)[lane];
        #pragma unroll
        for (int i = 0; i < W; ++i) {
            f32x4 a = rbase[(size_t)(w16 + i) * F4 + lane];
            float d = a.x * s4.x + a.y * s4.y + a.z * s4.z + a.w * s4.w;
            #pragma unroll
            for (int off = 32; off; off >>= 1) d += __shfl_xor(d, off);
            if (lane == 0) scoreS[w16 + i] = d;
        }
    }
    __syncthreads();

    // 4) wave0: top-3 min -> lock-free bubbling slot insert (exact top-3, order-free).
    if (wave == 0) {
        const unsigned gidx = (unsigned)(chunk * R + lane);   // R == 64 == lanes
        unsigned long long inv =
            ~((((unsigned long long)sortable_f32(scoreS[lane])) << 32) | (unsigned long long)gidx);
        unsigned long long cur = inv;
        for (int k = 0; k < 3; ++k) {
            unsigned long long m = cur;
            #pragma unroll
            for (int off = 32; off; off >>= 1) {
                unsigned long long o = __shfl_xor(m, off);
                if (o > m) m = o;
            }
            if (lane == 0) {
                unsigned long long x = m;
                #pragma unroll
                for (int s = 0; s < 3; ++s) {
                    unsigned long long old = atomicMax(&minslot[s], x);
                    x = (old < x) ? old : x;
                }
            }
            if (cur == m) cur = 0;
        }
    }

    // 5) Per-batch spin barrier. vmcnt(0) drains my slot atomics AND the sv stream
    //    (both issued long ago). sched_barrier stops reg-only hoisting (rule #18).
    //    All 512 blocks co-resident: 2 blocks/CU needed, >=4 fit (VGPR<=128, LDS ~2KB).
    asm volatile("s_waitcnt vmcnt(0)" ::: "memory");
    __builtin_amdgcn_sched_barrier(0);
    __syncthreads();
    if (t == 0) {
        int* c = cnt + b * 32;
        __hip_atomic_fetch_add(c, 1, __ATOMIC_RELAXED, __HIP_MEMORY_SCOPE_AGENT);
        while (__hip_atomic_load(c, __ATOMIC_RELAXED, __HIP_MEMORY_SCOPE_AGENT) < CH)
            __builtin_amdgcn_s_sleep(2);
    }
    __syncthreads();

    // 6) Decode top-3 (agent loads bypass stale cache), Tv, out rows 0-2.
    if (t == 0) {
        unsigned long long y0 = agent_load_u64(&minslot[0]);
        unsigned long long y1 = agent_load_u64(&minslot[1]);
        unsigned long long y2 = agent_load_u64(&minslot[2]);
        unsigned long long tmp;
        if (y1 > y0) { tmp = y0; y0 = y1; y1 = tmp; }
        if (y2 > y0) { tmp = y0; y0 = y2; y2 = tmp; }
        if (y2 > y1) { tmp = y1; y1 = y2; y2 = tmp; }
        chosen[0] = (int)((~y0) & 0xFFFFFFFFull);
        chosen[1] = (int)((~y1) & 0xFFFFFFFFull);
        chosen[2] = (int)((~y2) & 0xFFFFFFFFull);
    }
    __syncthreads();
    {
        const int i0 = chosen[0], i1 = chosen[1], i2 = chosen[2];
        S[t] = ref_flow[((size_t)b * N + i0) * F + t]     // read-only input: cache-safe
             + ref_flow[((size_t)b * N + i1) * F + t]
             + ref_flow[((size_t)b * N + i2) * F + t];    // S[] now holds Tv
        if (chunk == 0) {
            out[((size_t)b * 5 + 0) * F + t] = ref_rgb[((size_t)b * N + i0) * F + t];
            out[((size_t)b * 5 + 1) * F + t] = ref_rgb[((size_t)b * N + i1) * F + t];
            out[((size_t)b * 5 + 2) * F + t] = ref_rgb[((size_t)b * N + i2) * F + t];
        }
    }
    __syncthreads();

    // 7) dot2 on the register-resident sup rows; wave0: top-2 max slot insert.
    {
        f32x4 tv4 = reinterpret_cast<const f32x4*>(S)[lane];
        #pragma unroll
        for (int i = 0; i < W; ++i) {
            float d = sv[i].x * tv4.x + sv[i].y * tv4.y + sv[i].z * tv4.z + sv[i].w * tv4.w;
            #pragma unroll
            for (int off = 32; off; off >>= 1) d += __shfl_xor(d, off);
            if (lane == 0) scoreS[w16 + i] = d;
        }
    }
    __syncthreads();
    if (wave == 0) {
        // packed: larger == larger score, tie -> smaller index wins max
        const unsigned gidx = (unsigned)(chunk * R + lane);
        unsigned long long pk =
            (((unsigned long long)sortable_f32(scoreS[lane])) << 32) |
            (unsigned long long)(0xFFFFFFFFu - gidx);
        unsigned long long cur = pk;
        for (int k = 0; k < 2; ++k) {
            unsigned long long m = cur;
            #pragma unroll
            for (int off = 32; off; off >>= 1) {
                unsigned long long o = __shfl_xor(m, off);
                if (o > m) m = o;
            }
            if (lane == 0) {
                unsigned long long x = m;
                #pragma unroll
                for (int s = 0; s < 2; ++s) {
                    unsigned long long old = atomicMax(&maxslot[s], x);
                    x = (old < x) ? old : x;
                }
            }
            if (cur == m) cur = 0;
        }
    }

    // 8) Last arriver per batch (no spin) decodes top-2 and gathers rows 3-4.
    asm volatile("s_waitcnt vmcnt(0)" ::: "memory");
    __syncthreads();
    if (t == 0) {
        int old = __hip_atomic_fetch_add(cnt + (B + b) * 32, 1,
                                         __ATOMIC_RELAXED, __HIP_MEMORY_SCOPE_AGENT);
        lastFlag = (old == CH - 1);
    }
    __syncthreads();
    if (lastFlag) {
        if (t == 0) {
            unsigned long long y0 = agent_load_u64(&maxslot[0]);
            unsigned long long y1 = agent_load_u64(&maxslot[1]);
            if (y1 > y0) { unsigned long long tmp = y0; y0 = y1; y1 = tmp; }
            chosen[0] = (int)(0xFFFFFFFFu - (unsigned)(y0 & 0xFFFFFFFFull));
            chosen[1] = (int)(0xFFFFFFFFu - (unsigned)(y1 & 0xFFFFFFFFull));
        }
        __syncthreads();
        out[((size_t)b * 5 + 3) * F + t] = sup_rgb[((size_t)b * N + chosen[0]) * F + t];
        out[((size_t)b * 5 + 4) * F + t] = sup_rgb[((size_t)b * N + chosen[1]) * F + t];
    }
}

extern "C" void kernel_launch(void* const* d_in, const int* in_sizes, int n_in,
                              void* d_out, int out_size, void* d_ws, size_t ws_size,
                              hipStream_t stream) {
    const float* ref_rgb  = (const float*)d_in[0];
    const float* ref_flow = (const float*)d_in[1];
    const float* sup_rgb  = (const float*)d_in[2];
    const float* sup_flow = (const float*)d_in[3];
    float* out = (float*)d_out;

    // ws: [0,2048) counters (2 sets x 8 batches x 128B) | [4096,5120) minslots |
    //     [8192,9216) maxslots | [16384, +512KB) partial
    int* cnt = (int*)d_ws;
    unsigned long long* minbase = (unsigned long long*)((char*)d_ws + 4096);
    unsigned long long* maxbase = (unsigned long long*)((char*)d_ws + 8192);
    float* partial = (float*)((char*)d_ws + 16384);

    kA_colsum<<<dim3(B, CH), 256, 0, stream>>>(ref_flow, partial, cnt, minbase, maxbase);
    kB_rest<<<dim3(B, CH), 256, 0, stream>>>(ref_rgb, ref_flow, sup_rgb, sup_flow,
                                             out, partial, minbase, maxbase, cnt);
}

// Round 11
// 44.417 us; speedup vs baseline: 1.0385x; 1.0385x over previous
//
#include <hip/hip_runtime.h>

// (B,N,F) = (8, 4096, 256), fp32 in/out. out = (B, 5, F).
constexpr int B = 8;
constexpr int N = 4096;
constexpr int F = 256;
constexpr int F4 = F / 4;        // 64 float4 per row
constexpr int CH = 64;           // chunks (blocks) per batch, all kernels
constexpr int R = N / CH;        // 64 rows per block
constexpr int W = R / 4;         // 16 rows per wave

// Monotone float->uint mapping: f<g  <=>  sortable(f)<sortable(g)
__device__ __forceinline__ unsigned sortable_f32(float f) {
    unsigned u = __float_as_uint(f);
    return (u & 0x80000000u) ? ~u : (u | 0x80000000u);
}

__device__ __forceinline__ unsigned long long agent_load_u64(const unsigned long long* p) {
    return __hip_atomic_load(p, __ATOMIC_RELAXED, __HIP_MEMORY_SCOPE_AGENT);
}

// ---------------- K1: column partials of ref_flow + zero-init ALL sync state ----------------
__global__ void k1_colsum(const float* __restrict__ ref_flow, float* __restrict__ partial,
                          int* __restrict__ cnt, unsigned long long* __restrict__ minbase,
                          unsigned long long* __restrict__ maxbase) {
    const int b = blockIdx.x, chunk = blockIdx.y;
    const int t = threadIdx.x, wave = t >> 6, lane = t & 63;
    const int w16 = wave * W;
    __shared__ float4 red[4][F4];

    const float4* rbase = reinterpret_cast<const float4*>(ref_flow)
                        + ((size_t)b * N + (size_t)chunk * R) * F4;
    // load-and-immediately-accumulate streaming (no prefetch-across-anything)
    float4 acc = make_float4(0.f, 0.f, 0.f, 0.f);
    #pragma unroll
    for (int i = 0; i < W; ++i) {
        float4 v = rbase[(size_t)(w16 + i) * F4 + lane];
        acc.x += v.x; acc.y += v.y; acc.z += v.z; acc.w += v.w;
    }
    red[wave][lane] = acc;
    __syncthreads();
    if (wave == 0) {
        float4 a0 = red[0][lane], a1 = red[1][lane], a2 = red[2][lane], a3 = red[3][lane];
        float4 s = make_float4(a0.x + a1.x + a2.x + a3.x, a0.y + a1.y + a2.y + a3.y,
                               a0.z + a1.z + a2.z + a3.z, a0.w + a1.w + a2.w + a3.w);
        reinterpret_cast<float4*>(partial)[((size_t)b * CH + chunk) * F4 + lane] = s;
    }
    // zero-init per-batch slots + both last-arriver counters (boundary-flushed to K2/K3)
    if (chunk == 0) {
        if (t < 3) minbase[(size_t)b * 16 + t] = 0ull;
        if (t < 2) maxbase[(size_t)b * 16 + t] = 0ull;
        if (t == 0) { cnt[b * 32] = 0; cnt[(B + b) * 32] = 0; }
    }
}

// ---------------- K2: redundant S-reduce (L2-cached) + dot1 + top3 -> slots;
//                      last-arriver: decode, Tv -> ws, out rows 0-2 ----------------
__global__ void k2_dot1(const float* __restrict__ ref_rgb, const float* __restrict__ ref_flow,
                        const float* __restrict__ partial, float* __restrict__ Tvg,
                        float* __restrict__ out,
                        unsigned long long* __restrict__ minbase, int* __restrict__ cnt) {
    const int b = blockIdx.x, chunk = blockIdx.y;
    const int t = threadIdx.x, wave = t >> 6, lane = t & 63;
    const int w16 = wave * W;
    __shared__ float S[F];
    __shared__ float scoreS[R];
    __shared__ int   chosen[3];
    __shared__ int   lastFlag;

    unsigned long long* minslot = minbase + (size_t)b * 16;

    // redundant S-reduce: same 64KB read by all 64 blocks of batch b -> L2 broadcast
    {
        float sacc = 0.f;
        const float* pb = partial + (size_t)b * CH * F + t;
        #pragma unroll 8
        for (int p = 0; p < CH; ++p) sacc += pb[(size_t)p * F];
        S[t] = sacc;
    }
    __syncthreads();

    // dot1: stream my ref rows (L3-hit after K1), load-FMA immediate
    const float4* rbase = reinterpret_cast<const float4*>(ref_flow)
                        + ((size_t)b * N + (size_t)chunk * R) * F4;
    {
        float4 s4 = reinterpret_cast<const float4*>(S)[lane];
        #pragma unroll
        for (int i = 0; i < W; ++i) {
            float4 a = rbase[(size_t)(w16 + i) * F4 + lane];
            float d = a.x * s4.x + a.y * s4.y + a.z * s4.z + a.w * s4.w;
            #pragma unroll
            for (int off = 32; off; off >>= 1) d += __shfl_xor(d, off);
            if (lane == 0) scoreS[w16 + i] = d;
        }
    }
    __syncthreads();

    // wave0: top-3 min -> lock-free bubbling slot insert (exact top-3, order-free)
    if (wave == 0) {
        const unsigned gidx = (unsigned)(chunk * R + lane);   // R == 64 == lanes
        unsigned long long inv =
            ~((((unsigned long long)sortable_f32(scoreS[lane])) << 32) | (unsigned long long)gidx);
        unsigned long long cur = inv;
        for (int k = 0; k < 3; ++k) {
            unsigned long long m = cur;
            #pragma unroll
            for (int off = 32; off; off >>= 1) {
                unsigned long long o = __shfl_xor(m, off);
                if (o > m) m = o;
            }
            if (lane == 0) {
                unsigned long long x = m;
                #pragma unroll
                for (int s = 0; s < 3; ++s) {
                    unsigned long long old = atomicMax(&minslot[s], x);
                    x = (old < x) ? old : x;
                }
            }
            if (cur == m) cur = 0;
        }
    }

    // last arriver per batch (no spin): decode top-3, build Tv, write out rows 0-2
    asm volatile("s_waitcnt vmcnt(0)" ::: "memory");   // my slot atomics globally visible
    __syncthreads();
    if (t == 0) {
        int old = __hip_atomic_fetch_add(cnt + b * 32, 1,
                                         __ATOMIC_RELAXED, __HIP_MEMORY_SCOPE_AGENT);
        lastFlag = (old == CH - 1);
    }
    __syncthreads();
    if (lastFlag) {
        if (t == 0) {
            unsigned long long y0 = agent_load_u64(&minslot[0]);
            unsigned long long y1 = agent_load_u64(&minslot[1]);
            unsigned long long y2 = agent_load_u64(&minslot[2]);
            unsigned long long tmp;
            if (y1 > y0) { tmp = y0; y0 = y1; y1 = tmp; }
            if (y2 > y0) { tmp = y0; y0 = y2; y2 = tmp; }
            if (y2 > y1) { tmp = y1; y1 = y2; y2 = tmp; }
            chosen[0] = (int)((~y0) & 0xFFFFFFFFull);
            chosen[1] = (int)((~y1) & 0xFFFFFFFFull);
            chosen[2] = (int)((~y2) & 0xFFFFFFFFull);
        }
        __syncthreads();
        const int i0 = chosen[0], i1 = chosen[1], i2 = chosen[2];
        Tvg[(size_t)b * F + t] = ref_flow[((size_t)b * N + i0) * F + t]
                               + ref_flow[((size_t)b * N + i1) * F + t]
                               + ref_flow[((size_t)b * N + i2) * F + t];
        out[((size_t)b * 5 + 0) * F + t] = ref_rgb[((size_t)b * N + i0) * F + t];
        out[((size_t)b * 5 + 1) * F + t] = ref_rgb[((size_t)b * N + i1) * F + t];
        out[((size_t)b * 5 + 2) * F + t] = ref_rgb[((size_t)b * N + i2) * F + t];
    }
}

// ---------------- K3: Tv load -> immediate cold sup stream (load-FMA) + top2 -> slots;
//                      last-arriver: decode + gather rows 3-4 ----------------
__global__ void k3_dot2(const float* __restrict__ sup_rgb, const float* __restrict__ sup_flow,
                        const float* __restrict__ Tvg, float* __restrict__ out,
                        unsigned long long* __restrict__ maxbase, int* __restrict__ cnt) {
    const int b = blockIdx.x, chunk = blockIdx.y;
    const int t = threadIdx.x, wave = t >> 6, lane = t & 63;
    const int w16 = wave * W;
    __shared__ float scoreS[R];
    __shared__ int   chosen[2];
    __shared__ int   lastFlag;

    unsigned long long* maxslot = maxbase + (size_t)b * 16;

    // one 16B load of Tv, then the cold 32MB sup stream starts immediately
    float4 tv4 = reinterpret_cast<const float4*>(Tvg)[(size_t)b * F4 + lane];
    const float4* sbase = reinterpret_cast<const float4*>(sup_flow)
                        + ((size_t)b * N + (size_t)chunk * R) * F4;
    #pragma unroll
    for (int i = 0; i < W; ++i) {
        float4 a = sbase[(size_t)(w16 + i) * F4 + lane];
        float d = a.x * tv4.x + a.y * tv4.y + a.z * tv4.z + a.w * tv4.w;
        #pragma unroll
        for (int off = 32; off; off >>= 1) d += __shfl_xor(d, off);
        if (lane == 0) scoreS[w16 + i] = d;
    }
    __syncthreads();

    if (wave == 0) {
        // packed: larger == larger score, tie -> smaller index wins max
        const unsigned gidx = (unsigned)(chunk * R + lane);
        unsigned long long pk =
            (((unsigned long long)sortable_f32(scoreS[lane])) << 32) |
            (unsigned long long)(0xFFFFFFFFu - gidx);
        unsigned long long cur = pk;
        for (int k = 0; k < 2; ++k) {
            unsigned long long m = cur;
            #pragma unroll
            for (int off = 32; off; off >>= 1) {
                unsigned long long o = __shfl_xor(m, off);
                if (o > m) m = o;
            }
            if (lane == 0) {
                unsigned long long x = m;
                #pragma unroll
                for (int s = 0; s < 2; ++s) {
                    unsigned long long old = atomicMax(&maxslot[s], x);
                    x = (old < x) ? old : x;
                }
            }
            if (cur == m) cur = 0;
        }
    }

    // last arriver per batch (no spin) decodes top-2 and gathers rows 3-4
    asm volatile("s_waitcnt vmcnt(0)" ::: "memory");
    __syncthreads();
    if (t == 0) {
        int old = __hip_atomic_fetch_add(cnt + (B + b) * 32, 1,
                                         __ATOMIC_RELAXED, __HIP_MEMORY_SCOPE_AGENT);
        lastFlag = (old == CH - 1);
    }
    __syncthreads();
    if (lastFlag) {
        if (t == 0) {
            unsigned long long y0 = agent_load_u64(&maxslot[0]);
            unsigned long long y1 = agent_load_u64(&maxslot[1]);
            if (y1 > y0) { unsigned long long tmp = y0; y0 = y1; y1 = tmp; }
            chosen[0] = (int)(0xFFFFFFFFu - (unsigned)(y0 & 0xFFFFFFFFull));
            chosen[1] = (int)(0xFFFFFFFFu - (unsigned)(y1 & 0xFFFFFFFFull));
        }
        __syncthreads();
        out[((size_t)b * 5 + 3) * F + t] = sup_rgb[((size_t)b * N + chosen[0]) * F + t];
        out[((size_t)b * 5 + 4) * F + t] = sup_rgb[((size_t)b * N + chosen[1]) * F + t];
    }
}

extern "C" void kernel_launch(void* const* d_in, const int* in_sizes, int n_in,
                              void* d_out, int out_size, void* d_ws, size_t ws_size,
                              hipStream_t stream) {
    const float* ref_rgb  = (const float*)d_in[0];
    const float* ref_flow = (const float*)d_in[1];
    const float* sup_rgb  = (const float*)d_in[2];
    const float* sup_flow = (const float*)d_in[3];
    float* out = (float*)d_out;

    // ws: [0,2048) counters (2 sets x 8 batches x 128B) | [4096,5120) minslots |
    //     [8192,9216) maxslots | [12288,20480) Tv (8 x 256 f32) | [32768,...) partial
    int* cnt = (int*)d_ws;
    unsigned long long* minbase = (unsigned long long*)((char*)d_ws + 4096);
    unsigned long long* maxbase = (unsigned long long*)((char*)d_ws + 8192);
    float* Tvg     = (float*)((char*)d_ws + 12288);
    float* partial = (float*)((char*)d_ws + 32768);

    k1_colsum<<<dim3(B, CH), 256, 0, stream>>>(ref_flow, partial, cnt, minbase, maxbase);
    k2_dot1<<<dim3(B, CH), 256, 0, stream>>>(ref_rgb, ref_flow, partial, Tvg, out, minbase, cnt);
    k3_dot2<<<dim3(B, CH), 256, 0, stream>>>(sup_rgb, sup_flow, Tvg, out, maxbase, cnt);
}